// Round 2
// baseline (143.352 us; speedup 1.0000x reference)
//
#include <hip/hip_runtime.h>
#include <math.h>

// Focal_loss2 — R15: occupancy doubling.
// R14 post-mortem: atomic-tail removal + NT revert worked (fused dropped off
// the top-5; total 166->142). Remaining fused time (~32us est) vs ~7us HBM
// floor with ALL pipes idle and Occupancy 16% -> memory-LATENCY bound: 577
// blocks / 256 CUs = 2.25 blocks/CU (~9 waves/CU) cannot hide ~500cy VMEM
// latency. Fix: halve y-chunk 8->4 rows (march 6 rows not 10), doubling the
// neg grid to 1152 blocks = 4.5 blocks/CU (~18 waves/CU). Halo overhead
// 1.25x->1.5x on logits is free (we're at 9% HBM BW).
//   neg: w = sigmoid(x)^2 * (gt==-1) * (x is 3x3x3 local max); loss += softplus(x)*w
//        local-max test in logit space (monotone sigmoid; validated R3-R14, absmax 0.0)
//   pos: 64 coords/batch/level gather; w1=(1-sigmoid)^2; per-(b,tag) min of w1
// ws layout (floats): [2*bid],[2*bid+1] = {loss,wsum} partial for neg block
//   bid in [0,1152); [2304..2307] = losspos_a,cntpos_a,losspos_b,cntpos_b
// out: [0]=cls_loss_pos [1]=cls_loss_neg [2]=count_pos [3]=count_neg
//      [4]=wsum_pos [5]=wsum_neg [6..37]=pred_prob_min[2][B=2][T=8]

#define NBLK_A 1024   // 4 vol x 8 z-groups(16 z) x 32 y-chunks(4 y)
#define NBLK_B 128    // 4 vol x 2 z-groups(32 z) x 16 y-chunks(4 y)
#define NBLK_NEG (NBLK_A + NBLK_B)
#define NBLK_TOTAL (NBLK_NEG + 1)
#define WS_POS 2304   // 2*NBLK_NEG

using f4 = __attribute__((ext_vector_type(4))) float;
using f2 = __attribute__((ext_vector_type(2))) float;

__device__ __forceinline__ float fmax3(float a, float b, float c) {
    return fmaxf(a, fmaxf(b, c));
}

__device__ __forceinline__ f4 fmax3v(f4 a, f4 b, f4 c) {
    f4 r;
    r.x = fmax3(a.x, b.x, c.x); r.y = fmax3(a.y, b.y, c.y);
    r.z = fmax3(a.z, b.z, c.z); r.w = fmax3(a.w, b.w, c.w);
    return r;
}

// Emit one output quad. x-halo via wave shuffle (xq in low lane bits; group
// edges overridden by the clamp rule).
template <int XQ>
__device__ __forceinline__ void emit_row(
    const f4 zw0, const f4 zw1, const f4 zw2, const f4 c, const f4 g,
    int xq, float& loss, float& wsum)
{
    f4 cz = fmax3v(zw0, zw1, zw2);                    // y-fold
    float lco = __shfl_up(cz.w, 1);   if (xq == 0)      lco = cz.x;
    float rco = __shfl_down(cz.x, 1); if (xq == XQ - 1) rco = cz.w;
    float ms[4] = {fmax3(lco, cz.x, cz.y), fmax3(cz.x, cz.y, cz.z),
                   fmax3(cz.y, cz.z, cz.w), fmax3(cz.z, cz.w, rco)};
    float cs[4] = {c.x, c.y, c.z, c.w};
    float gs[4] = {g.x, g.y, g.z, g.w};
#pragma unroll
    for (int k = 0; k < 4; ++k) {
        if (gs[k] == -1.0f && ms[k] == cs[k]) {
            float e = __expf(cs[k]);                  // e^x
            float u = __builtin_amdgcn_rcpf(1.0f + e);
            float sc = e * u;                         // sigmoid(x)
            float wv = sc * sc;
            wsum += wv;
            loss += (-__logf(u)) * wv;                // softplus(x)
        }
    }
}

// One thread: fixed (x-quad, z-pair). Marches y0-1..y0+4 (6 rows, clamped),
// emitting 4 y-rows at BOTH z and z+1 from 4 planes z-1..z+2 (z-pairing).
// Logit loads are PLAIN (L1 absorbs plane/halo re-reads — NT regressed, R13).
// gt rows are single-use -> non-temporal. Boundary: index clamping duplicates
// an in-window value -> max unchanged.
template <int D, int LOG2D, int XQ>
__device__ __forceinline__ void neg_march2(
    const float* __restrict__ logits, const float* __restrict__ gt,
    int vol, int z, int y0, int xq, float& loss, float& wsum)
{
    const int x0 = xq << 2;
    const float* vb = logits + (vol << (3 * LOG2D));
    const int zm = z > 0 ? z - 1 : 0;              // z+1 <= D-1 by construction
    const int zq = z + 2 < D ? z + 2 : D - 1;
    const float* p0 = vb + (zm << (2 * LOG2D));
    const float* p1 = vb + (z << (2 * LOG2D));
    const float* p2 = vb + ((z + 1) << (2 * LOG2D));
    const float* p3 = vb + (zq << (2 * LOG2D));
    const float* g1 = gt + (vol << (3 * LOG2D)) + (z << (2 * LOG2D));
    const float* g2 = g1 + (1 << (2 * LOG2D));

    f4 za[3], zb[3];   // rings: z-folded col max for output z / z+1
    f4 ca[2], cb[2];   // rings: center raw quads (plane z / z+1)
    f4 ga[2], gb[2];   // rings: gt quads

#pragma unroll
    for (int s = 0; s < 6; ++s) {
        int yy = y0 - 1 + s;
        yy = yy < 0 ? 0 : (yy > D - 1 ? D - 1 : yy);
        const int ro = (yy << LOG2D) + x0;
        f4 r0 = *(const f4*)(p0 + ro);
        f4 r1 = *(const f4*)(p1 + ro);
        f4 r2 = *(const f4*)(p2 + ro);
        f4 r3 = *(const f4*)(p3 + ro);
        if (s >= 1 && s <= 4) {       // gt rows: single-use stream
            ga[s & 1] = __builtin_nontemporal_load((const f4*)(g1 + ro));
            gb[s & 1] = __builtin_nontemporal_load((const f4*)(g2 + ro));
        }
        za[s % 3] = fmax3v(r0, r1, r2);
        zb[s % 3] = fmax3v(r1, r2, r3);
        ca[s & 1] = r1;
        cb[s & 1] = r2;
        if (s >= 2) {
            // order-insensitive: fmax3v over all three ring slots
            emit_row<XQ>(za[0], za[1], za[2], ca[(s - 1) & 1], ga[(s - 1) & 1],
                         xq, loss, wsum);
            emit_row<XQ>(zb[0], zb[1], zb[2], cb[(s - 1) & 1], gb[(s - 1) & 1],
                         xq, loss, wsum);
        }
    }
}

__global__ __launch_bounds__(256, 4) void fused_kernel(
    const float* __restrict__ la, const float* __restrict__ lb,
    const float* __restrict__ ga, const float* __restrict__ gb,
    const int* __restrict__ conn_a, const int* __restrict__ conn_b,
    const int* __restrict__ coord_a, const int* __restrict__ coord_b,
    float* __restrict__ ws, float* __restrict__ out)
{
    __shared__ float sred[8];
    __shared__ float w1s[128];
    __shared__ float tgf[128];
    const int bid = blockIdx.x;
    const int t = threadIdx.x;
    float loss = 0.0f, wsum = 0.0f;
    bool isNeg = false;

    if (bid < NBLK_A) {
        // level a: D=128. xq = t&31, z-pair = t>>5 (block: 16 z x 8 y... now
        // 16 z x 4 y via 32 y-chunks). XCD swizzle: xcd = bid&7 owns z-group c.
        isNeg = true;
        const int c = bid & 7;
        const int g = bid >> 3;        // 0..127
        const int yc = g & 31;         // y fastest
        const int vol = g >> 5;
        neg_march2<128, 7, 32>(la, ga, vol, c * 16 + (t >> 5) * 2, yc * 4,
                               t & 31, loss, wsum);
    } else if (bid < NBLK_NEG) {
        // level b: D=64. xq = t&15, z-pair = t>>4.
        isNeg = true;
        const int b2 = bid - NBLK_A;
        const int c = b2 & 7;
        const int yc = b2 >> 3;        // 0..15
        const int vol = c >> 1;
        const int zg = c & 1;
        neg_march2<64, 6, 16>(lb, gb, vol, zg * 32 + (t >> 4) * 2, yc * 4,
                              t & 15, loss, wsum);
    } else {
        // pos block: both levels, 128 active threads. Single writer of the
        // pos partials and out[6..37] -> plain stores, no atomics.
        for (int level = 0; level < 2; ++level) {
            const float* logits = level ? lb : la;
            const int* conn = level ? conn_b : conn_a;
            const int* coord = level ? coord_b : coord_a;
            const int D = level ? 64 : 128;
            float li = 0.0f, ci = 0.0f;
            if (t < 128) {
                const int* c4 = coord + t * 4;
                int a = c4[0], zz = c4[1], yy = c4[2], xx = c4[3];
                bool valid = a > -1;
                int aa = valid ? a : 0, z2 = valid ? zz : 0,
                    y2 = valid ? yy : 0, x2 = valid ? xx : 0;
                int b = t >> 6;
                int off = (((b * 2 + aa) * D + z2) * D + y2) * D + x2;
                float lp = logits[off];
                int tag = conn[off];
                float s = 1.0f / (1.0f + expf(lp));   // 1 - sigmoid(lp)
                float w1 = s * s;
                float vf = valid ? 1.0f : 0.0f;
                float sp = fmaxf(-lp, 0.0f) + log1pf(expf(-fabsf(lp)));  // softplus(-lp)
                li = sp * w1 * vf;
                ci = w1 * vf;
                w1s[t] = w1;
                tgf[t] = (float)(valid ? tag : -1);
            }
            for (int o = 32; o; o >>= 1) {
                li += __shfl_down(li, o);
                ci += __shfl_down(ci, o);
            }
            if ((t & 63) == 0) { sred[t >> 6] = li; sred[4 + (t >> 6)] = ci; }
            __syncthreads();
            if (t == 0) {
                ws[WS_POS + 2 * level]     = sred[0] + sred[1] + sred[2] + sred[3];
                ws[WS_POS + 2 * level + 1] = sred[4] + sred[5] + sred[6] + sred[7];
            }
            if (t < 16) {
                int bb = t >> 3, tg = t & 7;
                float mn = INFINITY;
                for (int i = 0; i < 64; ++i) {
                    int j = bb * 64 + i;
                    if (tgf[j] == (float)tg) mn = fminf(mn, w1s[j]);
                }
                out[6 + level * 16 + bb * 8 + tg] = isinf(mn) ? -1.0f : mn;
            }
            __syncthreads();
        }
    }

    if (isNeg) {
        for (int o = 32; o; o >>= 1) {
            loss += __shfl_down(loss, o);
            wsum += __shfl_down(wsum, o);
        }
        if ((t & 63) == 0) { sred[t >> 6] = loss; sred[4 + (t >> 6)] = wsum; }
        __syncthreads();
        if (t == 0) {
            f2 v;
            v.x = sred[0] + sred[1] + sred[2] + sred[3];
            v.y = sred[4] + sred[5] + sred[6] + sred[7];
            ((f2*)ws)[bid] = v;    // private 8B slot, zero contention
        }
    }
}

// Stream-ordered finalize: reduces the 1152 block partials. No arrival
// counter, no fence — dispatch boundary provides ordering + visibility.
__global__ __launch_bounds__(256) void finalize_kernel(
    const float* __restrict__ ws, float* __restrict__ out)
{
    __shared__ float sred[32];
    const int t = threadIdx.x;
    float la = 0.0f, wa = 0.0f, lb = 0.0f, wb = 0.0f;
    for (int i = t; i < NBLK_NEG; i += 256) {
        f2 v = ((const f2*)ws)[i];
        if (i < NBLK_A) { la += v.x; wa += v.y; }
        else            { lb += v.x; wb += v.y; }
    }
    for (int o = 32; o; o >>= 1) {
        la += __shfl_down(la, o);
        wa += __shfl_down(wa, o);
        lb += __shfl_down(lb, o);
        wb += __shfl_down(wb, o);
    }
    if ((t & 63) == 0) {
        int w = t >> 6;
        sred[w] = la; sred[8 + w] = wa; sred[16 + w] = lb; sred[24 + w] = wb;
    }
    __syncthreads();
    if (t == 0) {
        float s0 = 0, s1 = 0, s2 = 0, s3 = 0;
        for (int w = 0; w < 4; ++w) {
            s0 += sred[w]; s1 += sred[8 + w]; s2 += sred[16 + w]; s3 += sred[24 + w];
        }
        float lpa = ws[WS_POS + 0], cpa = ws[WS_POS + 1];
        float lpb = ws[WS_POS + 2], cpb = ws[WS_POS + 3];
        out[0] = lpa * 2.0f + lpb;   // cls_loss_pos (POS_FACTOR {2,1})
        out[1] = s0 * 2.0f + s2;     // cls_loss_neg (NEG_FACTOR {2,1})
        out[2] = cpa + cpb;          // count_pos
        out[3] = s1 + s3;            // count_neg
        out[4] = cpa * 2.0f + cpb;   // wsum_pos (anchor factor == 1)
        out[5] = s1 * 2.0f + s3;     // wsum_neg
    }
}

extern "C" void kernel_launch(void* const* d_in, const int* in_sizes, int n_in,
                              void* d_out, int out_size, void* d_ws, size_t ws_size,
                              hipStream_t stream) {
    const float* logits_a = (const float*)d_in[0];
    const float* logits_b = (const float*)d_in[1];
    const float* prob_a   = (const float*)d_in[2];
    const float* prob_b   = (const float*)d_in[3];
    const int*   conn_a   = (const int*)d_in[4];
    const int*   conn_b   = (const int*)d_in[5];
    const int*   coord_a  = (const int*)d_in[6];
    const int*   coord_b  = (const int*)d_in[7];
    float* out = (float*)d_out;
    float* ws  = (float*)d_ws;

    // No memset: every ws slot is unconditionally overwritten each iteration.
    fused_kernel<<<NBLK_TOTAL, 256, 0, stream>>>(
        logits_a, logits_b, prob_a, prob_b,
        conn_a, conn_b, coord_a, coord_b, ws, out);
    finalize_kernel<<<1, 256, 0, stream>>>(ws, out);
}

// Round 3
// 141.183 us; speedup vs baseline: 1.0154x; 1.0154x over previous
//
#include <hip/hip_runtime.h>
#include <math.h>

// Focal_loss2 — R16: balanced 3-blocks/CU grid under the L1-miss-fill model.
// R15 falsified TLP-latency theory (2x occupancy -> +1.6us). Model that fits
// all points: per-CU L1 miss-fill throughput cap ~6 B/cy (MSHR x latency);
// kernel time = worst-CU unique-miss bytes / cap. Levers: halo duplication
// and per-CU block balance. R16: grid = 512 A-blocks (zc=16,yc=8, lowest-dup
// validated geometry) + 256 B-blocks (zc=16,yc=4, 128 active threads) + 1 pos
// = 769 -> every CU gets 2A+1B = 359 KB misses vs R14's worst 473 KB.
//   neg: w = sigmoid(x)^2 * (gt==-1) * (x is 3x3x3 local max); loss += softplus(x)*w
//        local-max test in logit space (monotone sigmoid; validated R3-R15, absmax 0.0)
//   pos: 64 coords/batch/level gather; w1=(1-sigmoid)^2; per-(b,tag) min of w1
// Load policy: logits PLAIN (L1 reuse; NT regressed R13), gt NT (single-use).
// No global atomics (R14): per-block f2 partial -> stream-ordered finalize.
// ws layout (floats): [2*bid],[2*bid+1] = {loss,wsum} for neg bid in [0,768);
//   [1536..1539] = losspos_a,cntpos_a,losspos_b,cntpos_b
// out: [0]=cls_loss_pos [1]=cls_loss_neg [2]=count_pos [3]=count_neg
//      [4]=wsum_pos [5]=wsum_neg [6..37]=pred_prob_min[2][B=2][T=8]

#define NBLK_A 512    // 4 vol x 8 z-groups(16 z) x 16 y-chunks(8 y)
#define NBLK_B 256    // 4 vol x 4 z-groups(16 z) x 16 y-chunks(4 y)
#define NBLK_NEG (NBLK_A + NBLK_B)
#define NBLK_TOTAL (NBLK_NEG + 1)
#define WS_POS 1536   // 2*NBLK_NEG

using f4 = __attribute__((ext_vector_type(4))) float;
using f2 = __attribute__((ext_vector_type(2))) float;

__device__ __forceinline__ float fmax3(float a, float b, float c) {
    return fmaxf(a, fmaxf(b, c));
}

__device__ __forceinline__ f4 fmax3v(f4 a, f4 b, f4 c) {
    f4 r;
    r.x = fmax3(a.x, b.x, c.x); r.y = fmax3(a.y, b.y, c.y);
    r.z = fmax3(a.z, b.z, c.z); r.w = fmax3(a.w, b.w, c.w);
    return r;
}

// Emit one output quad. x-halo via wave shuffle (xq in low lane bits; group
// edges overridden by the clamp rule).
template <int XQ>
__device__ __forceinline__ void emit_row(
    const f4 zw0, const f4 zw1, const f4 zw2, const f4 c, const f4 g,
    int xq, float& loss, float& wsum)
{
    f4 cz = fmax3v(zw0, zw1, zw2);                    // y-fold
    float lco = __shfl_up(cz.w, 1);   if (xq == 0)      lco = cz.x;
    float rco = __shfl_down(cz.x, 1); if (xq == XQ - 1) rco = cz.w;
    float ms[4] = {fmax3(lco, cz.x, cz.y), fmax3(cz.x, cz.y, cz.z),
                   fmax3(cz.y, cz.z, cz.w), fmax3(cz.z, cz.w, rco)};
    float cs[4] = {c.x, c.y, c.z, c.w};
    float gs[4] = {g.x, g.y, g.z, g.w};
#pragma unroll
    for (int k = 0; k < 4; ++k) {
        if (gs[k] == -1.0f && ms[k] == cs[k]) {
            float e = __expf(cs[k]);                  // e^x
            float u = __builtin_amdgcn_rcpf(1.0f + e);
            float sc = e * u;                         // sigmoid(x)
            float wv = sc * sc;
            wsum += wv;
            loss += (-__logf(u)) * wv;                // softplus(x)
        }
    }
}

// One thread: fixed (x-quad, z-pair). Marches y0-1..y0+YR (YR+2 rows,
// clamped), emitting YR y-rows at BOTH z and z+1 from 4 planes z-1..z+2.
// Logit loads PLAIN, gt rows NT. Boundary: index clamping duplicates an
// in-window value -> max unchanged.
template <int D, int LOG2D, int XQ, int YR>
__device__ __forceinline__ void neg_march2(
    const float* __restrict__ logits, const float* __restrict__ gt,
    int vol, int z, int y0, int xq, float& loss, float& wsum)
{
    const int x0 = xq << 2;
    const float* vb = logits + (vol << (3 * LOG2D));
    const int zm = z > 0 ? z - 1 : 0;              // z+1 <= D-1 by construction
    const int zq = z + 2 < D ? z + 2 : D - 1;
    const float* p0 = vb + (zm << (2 * LOG2D));
    const float* p1 = vb + (z << (2 * LOG2D));
    const float* p2 = vb + ((z + 1) << (2 * LOG2D));
    const float* p3 = vb + (zq << (2 * LOG2D));
    const float* g1 = gt + (vol << (3 * LOG2D)) + (z << (2 * LOG2D));
    const float* g2 = g1 + (1 << (2 * LOG2D));

    f4 za[3], zb[3];   // rings: z-folded col max for output z / z+1
    f4 ca[2], cb[2];   // rings: center raw quads (plane z / z+1)
    f4 ga[2], gb[2];   // rings: gt quads

#pragma unroll
    for (int s = 0; s < YR + 2; ++s) {
        int yy = y0 - 1 + s;
        yy = yy < 0 ? 0 : (yy > D - 1 ? D - 1 : yy);
        const int ro = (yy << LOG2D) + x0;
        f4 r0 = *(const f4*)(p0 + ro);
        f4 r1 = *(const f4*)(p1 + ro);
        f4 r2 = *(const f4*)(p2 + ro);
        f4 r3 = *(const f4*)(p3 + ro);
        if (s >= 1 && s <= YR) {      // gt rows: single-use stream
            ga[s & 1] = __builtin_nontemporal_load((const f4*)(g1 + ro));
            gb[s & 1] = __builtin_nontemporal_load((const f4*)(g2 + ro));
        }
        za[s % 3] = fmax3v(r0, r1, r2);
        zb[s % 3] = fmax3v(r1, r2, r3);
        ca[s & 1] = r1;
        cb[s & 1] = r2;
        if (s >= 2) {
            emit_row<XQ>(za[0], za[1], za[2], ca[(s - 1) & 1], ga[(s - 1) & 1],
                         xq, loss, wsum);
            emit_row<XQ>(zb[0], zb[1], zb[2], cb[(s - 1) & 1], gb[(s - 1) & 1],
                         xq, loss, wsum);
        }
    }
}

__global__ __launch_bounds__(256, 4) void fused_kernel(
    const float* __restrict__ la, const float* __restrict__ lb,
    const float* __restrict__ ga, const float* __restrict__ gb,
    const int* __restrict__ conn_a, const int* __restrict__ conn_b,
    const int* __restrict__ coord_a, const int* __restrict__ coord_b,
    float* __restrict__ ws, float* __restrict__ out)
{
    __shared__ float sred[8];
    __shared__ float w1s[128];
    __shared__ float tgf[128];
    const int bid = blockIdx.x;
    const int t = threadIdx.x;
    float loss = 0.0f, wsum = 0.0f;
    bool isNeg = false;

    if (bid < NBLK_A) {
        // level a: D=128, 256 threads: xq = t&31, z-pair = t>>5 (16 z x 8 y).
        // XCD swizzle: xcd = bid&7 owns z-group c (16 z) for all 4 vols.
        isNeg = true;
        const int c = bid & 7;
        const int g = bid >> 3;        // 0..63
        const int yc = g & 15;         // y fastest
        const int vol = g >> 4;
        neg_march2<128, 7, 32, 8>(la, ga, vol, c * 16 + (t >> 5) * 2, yc * 8,
                                  t & 31, loss, wsum);
    } else if (bid < NBLK_NEG) {
        // level b: D=64, 128 active threads: xq = t&15, z-pair = (t>>4)&7
        // (16 z x 4 y). vol/z-group-low from low bits (XCD spread), y fastest.
        isNeg = true;
        const int b2 = bid - NBLK_A;   // 0..255
        const int c = b2 & 7;
        const int vol = c >> 1;
        const int zg = (c & 1) * 2 + ((b2 >> 3) & 1);   // 0..3 (16 z each)
        const int yc = b2 >> 4;        // 0..15
        if (t < 128) {
            neg_march2<64, 6, 16, 4>(lb, gb, vol, zg * 16 + (t >> 4) * 2,
                                     yc * 4, t & 15, loss, wsum);
        }
    } else {
        // pos block: both levels, 128 active threads. Single writer of the
        // pos partials and out[6..37] -> plain stores, no atomics.
        for (int level = 0; level < 2; ++level) {
            const float* logits = level ? lb : la;
            const int* conn = level ? conn_b : conn_a;
            const int* coord = level ? coord_b : coord_a;
            const int D = level ? 64 : 128;
            float li = 0.0f, ci = 0.0f;
            if (t < 128) {
                const int* c4 = coord + t * 4;
                int a = c4[0], zz = c4[1], yy = c4[2], xx = c4[3];
                bool valid = a > -1;
                int aa = valid ? a : 0, z2 = valid ? zz : 0,
                    y2 = valid ? yy : 0, x2 = valid ? xx : 0;
                int b = t >> 6;
                int off = (((b * 2 + aa) * D + z2) * D + y2) * D + x2;
                float lp = logits[off];
                int tag = conn[off];
                float s = 1.0f / (1.0f + expf(lp));   // 1 - sigmoid(lp)
                float w1 = s * s;
                float vf = valid ? 1.0f : 0.0f;
                float sp = fmaxf(-lp, 0.0f) + log1pf(expf(-fabsf(lp)));  // softplus(-lp)
                li = sp * w1 * vf;
                ci = w1 * vf;
                w1s[t] = w1;
                tgf[t] = (float)(valid ? tag : -1);
            }
            for (int o = 32; o; o >>= 1) {
                li += __shfl_down(li, o);
                ci += __shfl_down(ci, o);
            }
            if ((t & 63) == 0) { sred[t >> 6] = li; sred[4 + (t >> 6)] = ci; }
            __syncthreads();
            if (t == 0) {
                ws[WS_POS + 2 * level]     = sred[0] + sred[1] + sred[2] + sred[3];
                ws[WS_POS + 2 * level + 1] = sred[4] + sred[5] + sred[6] + sred[7];
            }
            if (t < 16) {
                int bb = t >> 3, tg = t & 7;
                float mn = INFINITY;
                for (int i = 0; i < 64; ++i) {
                    int j = bb * 64 + i;
                    if (tgf[j] == (float)tg) mn = fminf(mn, w1s[j]);
                }
                out[6 + level * 16 + bb * 8 + tg] = isinf(mn) ? -1.0f : mn;
            }
            __syncthreads();
        }
    }

    if (isNeg) {
        for (int o = 32; o; o >>= 1) {
            loss += __shfl_down(loss, o);
            wsum += __shfl_down(wsum, o);
        }
        if ((t & 63) == 0) { sred[t >> 6] = loss; sred[4 + (t >> 6)] = wsum; }
        __syncthreads();
        if (t == 0) {
            f2 v;
            v.x = sred[0] + sred[1] + sred[2] + sred[3];
            v.y = sred[4] + sred[5] + sred[6] + sred[7];
            ((f2*)ws)[bid] = v;    // private 8B slot, zero contention
        }
    }
}

// Stream-ordered finalize: reduces the 768 block partials. No arrival
// counter, no fence — dispatch boundary provides ordering + visibility.
__global__ __launch_bounds__(256) void finalize_kernel(
    const float* __restrict__ ws, float* __restrict__ out)
{
    __shared__ float sred[32];
    const int t = threadIdx.x;
    float la = 0.0f, wa = 0.0f, lb = 0.0f, wb = 0.0f;
    for (int i = t; i < NBLK_NEG; i += 256) {
        f2 v = ((const f2*)ws)[i];
        if (i < NBLK_A) { la += v.x; wa += v.y; }
        else            { lb += v.x; wb += v.y; }
    }
    for (int o = 32; o; o >>= 1) {
        la += __shfl_down(la, o);
        wa += __shfl_down(wa, o);
        lb += __shfl_down(lb, o);
        wb += __shfl_down(wb, o);
    }
    if ((t & 63) == 0) {
        int w = t >> 6;
        sred[w] = la; sred[8 + w] = wa; sred[16 + w] = lb; sred[24 + w] = wb;
    }
    __syncthreads();
    if (t == 0) {
        float s0 = 0, s1 = 0, s2 = 0, s3 = 0;
        for (int w = 0; w < 4; ++w) {
            s0 += sred[w]; s1 += sred[8 + w]; s2 += sred[16 + w]; s3 += sred[24 + w];
        }
        float lpa = ws[WS_POS + 0], cpa = ws[WS_POS + 1];
        float lpb = ws[WS_POS + 2], cpb = ws[WS_POS + 3];
        out[0] = lpa * 2.0f + lpb;   // cls_loss_pos (POS_FACTOR {2,1})
        out[1] = s0 * 2.0f + s2;     // cls_loss_neg (NEG_FACTOR {2,1})
        out[2] = cpa + cpb;          // count_pos
        out[3] = s1 + s3;            // count_neg
        out[4] = cpa * 2.0f + cpb;   // wsum_pos (anchor factor == 1)
        out[5] = s1 * 2.0f + s3;     // wsum_neg
    }
}

extern "C" void kernel_launch(void* const* d_in, const int* in_sizes, int n_in,
                              void* d_out, int out_size, void* d_ws, size_t ws_size,
                              hipStream_t stream) {
    const float* logits_a = (const float*)d_in[0];
    const float* logits_b = (const float*)d_in[1];
    const float* prob_a   = (const float*)d_in[2];
    const float* prob_b   = (const float*)d_in[3];
    const int*   conn_a   = (const int*)d_in[4];
    const int*   conn_b   = (const int*)d_in[5];
    const int*   coord_a  = (const int*)d_in[6];
    const int*   coord_b  = (const int*)d_in[7];
    float* out = (float*)d_out;
    float* ws  = (float*)d_ws;

    // No memset: every ws slot is unconditionally overwritten each iteration.
    fused_kernel<<<NBLK_TOTAL, 256, 0, stream>>>(
        logits_a, logits_b, prob_a, prob_b,
        conn_a, conn_b, coord_a, coord_b, ws, out);
    finalize_kernel<<<1, 256, 0, stream>>>(ws, out);
}